// Round 6
// baseline (4462.774 us; speedup 1.0000x reference)
//
#include <hip/hip_runtime.h>
#include <cstddef>

#define T_  128
#define B_  64
#define F_  75
#define H_  512
#define G4_ 2048
#define TB_ (T_ * B_)
#define KP_ 128   // padded K for F=75 inputs

typedef __bf16 bf16x8 __attribute__((ext_vector_type(8)));
typedef float  f32x4  __attribute__((ext_vector_type(4)));
typedef unsigned long long u64;

__device__ __forceinline__ short f2b(float x) {
    union { float f; unsigned u; } v; v.f = x;
    return (short)((v.u + 0x7fffu + ((v.u >> 16) & 1u)) >> 16);
}
__device__ __forceinline__ float b2f(short s) {
    union { float f; unsigned u; } v; v.u = ((unsigned)(unsigned short)s) << 16;
    return v.f;
}
__device__ __forceinline__ void gload16(const void* g, void* l) {
    __builtin_amdgcn_global_load_lds(
        (const __attribute__((address_space(1))) void*)g,
        (__attribute__((address_space(3))) void*)l, 16, 0, 0);
}
__device__ __forceinline__ float fsig(float x) {
    return __builtin_amdgcn_rcpf(1.f + __expf(-x));
}
__device__ __forceinline__ float ftanh(float x) {
    return 1.f - 2.f * __builtin_amdgcn_rcpf(1.f + __expf(2.f * x));
}
__device__ __forceinline__ u64 aload(const u64* p) {
    return __hip_atomic_load(p, __ATOMIC_RELAXED, __HIP_MEMORY_SCOPE_AGENT);
}
__device__ __forceinline__ void astore(u64* p, u64 v) {
    __hip_atomic_store(p, v, __ATOMIC_RELAXED, __HIP_MEMORY_SCOPE_AGENT);
}

// ---------------------------------------------------------------------------
// bf16 MFMA GEMM. If P != null: write fp32 results into the step-kernel's
// packed XW layout  P[t][ub(32)][r(4)][tidS(256)][g(4)]  (biases included).
// Else: C(M,N) fp32 row-major.
// ---------------------------------------------------------------------------
__global__ __launch_bounds__(256) void gemm_bf16(
    const short* __restrict__ A, const short* __restrict__ Bm,
    float* __restrict__ C, float* __restrict__ P, int M, int N, int K,
    const float* __restrict__ bias1, const float* __restrict__ bias2)
{
    __shared__ short As[4096];
    __shared__ short Bs[4096];
    const int tid = threadIdx.x;
    const int m_base = blockIdx.y * 128;
    const int n_base = blockIdx.x * 128;
    const int w = tid >> 6, lane = tid & 63;
    const int wm = (w >> 1) * 64, wn = (w & 1) * 64;
    const int lm = lane & 15, q = lane >> 4;

    f32x4 acc[4][4];
#pragma unroll
    for (int i = 0; i < 4; i++)
#pragma unroll
        for (int j = 0; j < 4; j++)
#pragma unroll
            for (int r = 0; r < 4; r++) acc[i][j][r] = 0.f;

    const int s0 = tid, s1 = tid + 256;
    const int r0 = s0 & 127, c0 = s0 >> 7;
    const int r1 = s1 & 127, c1 = s1 >> 7;

    for (int k0 = 0; k0 < K; k0 += 32) {
        __syncthreads();
        gload16(A + (size_t)(m_base + r0) * K + k0 + c0 * 8, &As[s0 * 8]);
        gload16(A + (size_t)(m_base + r1) * K + k0 + c1 * 8, &As[s1 * 8]);
        gload16(Bm + (size_t)(n_base + r0) * K + k0 + c0 * 8, &Bs[s0 * 8]);
        gload16(Bm + (size_t)(n_base + r1) * K + k0 + c1 * 8, &Bs[s1 * 8]);
        __syncthreads();
        bf16x8 af[4], bfv[4];
#pragma unroll
        for (int i = 0; i < 4; i++) {
            af[i]  = *(const bf16x8*)&As[((q * 128) + wm + i * 16 + lm) * 8];
            bfv[i] = *(const bf16x8*)&Bs[((q * 128) + wn + i * 16 + lm) * 8];
        }
#pragma unroll
        for (int i = 0; i < 4; i++)
#pragma unroll
            for (int j = 0; j < 4; j++)
                acc[i][j] = __builtin_amdgcn_mfma_f32_16x16x32_bf16(
                    af[i], bfv[j], acc[i][j], 0, 0, 0);
    }

#pragma unroll
    for (int i = 0; i < 4; i++) {
#pragma unroll
        for (int j = 0; j < 4; j++) {
            const int gm0 = m_base + wm + i * 16 + q * 4;
            const int gn = n_base + wn + j * 16 + lm;
            float bb = (bias1 ? bias1[gn] : 0.f) + (bias2 ? bias2[gn] : 0.f);
            if (P) {
                const int g = gn >> 9, u = gn & 511;
                const int ub = u >> 4, lmu = u & 15;
#pragma unroll
                for (int r = 0; r < 4; r++) {
                    const int gm = gm0 + r;
                    const int t = gm >> 6, b = gm & 63;
                    const int tidS = (b >> 4) * 64 + ((b >> 2) & 3) * 16 + lmu;
                    size_t idx = ((((size_t)t * 32 + ub) * 4 + (b & 3)) * 256 + tidS) * 4 + g;
                    P[idx] = acc[i][j][r] + bb;
                }
            } else {
#pragma unroll
                for (int r = 0; r < 4; r++)
                    C[(size_t)(gm0 + r) * N + gn] = acc[i][j][r] + bb;
            }
        }
    }
}

// ---------------------------------------------------------------------------
// Pack Whh (2,4H,H) fp32 -> bf16 B-fragments:
// Wpk[dir][ub(32)][g(4)][it(16)][lane(64)][8]
// ---------------------------------------------------------------------------
__global__ __launch_bounds__(256) void pack_whh(
    const float* __restrict__ W, short* __restrict__ Wpk)
{
    int i = blockIdx.x * 256 + threadIdx.x;
    if (i >= 2 * G4_ * H_) return;
    int e = i & 7, lane = (i >> 3) & 63, it = (i >> 9) & 15;
    int g = (i >> 13) & 3, ub = (i >> 15) & 31, dir = (i >> 20) & 1;
    int lm = lane & 15, qq = lane >> 4;
    float v = W[((size_t)dir * G4_ + g * H_ + ub * 16 + lm) * H_
                + it * 32 + qq * 8 + e];
    Wpk[i] = f2b(v);
}

// ---------------------------------------------------------------------------
__global__ __launch_bounds__(256) void init_phase(
    const float* __restrict__ h0s, short* __restrict__ Ht0)
{
    int i = blockIdx.x * 256 + threadIdx.x;
    if (i < 2 * B_ * H_) Ht0[i] = f2b(h0s[i]);
}

// Extract final hidden states from Hseq (T,B,2H): fwd at t=T-1, bwd at t=0.
__global__ __launch_bounds__(256) void extract_sahf(
    const short* __restrict__ Hseq, float* __restrict__ out)
{
    int i = blockIdx.x * 256 + threadIdx.x;
    if (i < 2 * B_ * H_) {
        int u = i & 511, b = (i >> 9) & 63, dir = i >> 15;
        int t = dir ? 0 : (T_ - 1);
        out[i] = b2f(Hseq[((size_t)t * B_ + b) * 1024 + dir * 512 + u]);
    }
}

// ---------------------------------------------------------------------------
// Persistent phase kernel, barrier-free data-flow sync. grid (32, 2).
// Hseq (= Y) is poison-initialized (0xFFFF); producers publish h slices as
// agent-scope u64 stores; consumers retry poisoned chunks. No fences/atomics
// RMW/drains on the critical path.
// ---------------------------------------------------------------------------
__global__ __launch_bounds__(256, 1) void lstm_phase(
    const float* __restrict__ XW,   // packed (2,T,32,4,256,4) fp32
    const short* __restrict__ Wpk,  // packed Whh bf16
    const short* __restrict__ Ht0,  // (2,B,H) bf16 initial h
    short* __restrict__ Hseq,       // (T,B,2H) bf16 = Y, poisoned 0xFFFF
    const float* __restrict__ c0p)  // (2,B,H) fp32 initial c
{
    __shared__ short Ws[32768];     // 64 KB packed weights
    __shared__ short Tb[2][64 * 24];
    const int dir = blockIdx.y, ub = blockIdx.x, u0 = ub * 16;
    const int tid = threadIdx.x, w = tid >> 6, lane = tid & 63;
    const int lm = lane & 15, q = lane >> 4;

    const short* wsrc = Wpk + (size_t)(dir * 32 + ub) * 32768;
#pragma unroll
    for (int p = 0; p < 16; p++)
        gload16(wsrc + (tid + 256 * p) * 8, &Ws[(tid + 256 * p) * 8]);

    const int b0 = w * 16 + q * 4;   // this lane's 4 batch rows (pointwise)
    const int r = w * 16 + lm;       // this lane's batch row (A-frag load)
    const int u = u0 + lm;           // this lane's hidden unit

    float c[4];
    f32x4 xw[4];
#pragma unroll
    for (int rr = 0; rr < 4; rr++)
        c[rr] = c0p[(size_t)dir * B_ * H_ + (size_t)(b0 + rr) * H_ + u];
    {
        const int t0 = dir ? (T_ - 1) : 0;
        const float* xp = XW + ((size_t)dir * T_ + t0) * (B_ * G4_) + (size_t)ub * 4096;
#pragma unroll
        for (int rr = 0; rr < 4; rr++)
            xw[rr] = *(const f32x4*)(xp + rr * 1024 + tid * 4);
    }
    __syncthreads();   // Ws resident

    for (int s = 0; s < T_; s++) {
        const int t = dir ? (T_ - 1 - s) : s;
        const int tp = dir ? (T_ - s) : (s - 1);      // previous step's t
        const short* hrow = (s == 0)
            ? (Ht0 + ((size_t)dir * B_ + r) * 512)
            : (Hseq + ((size_t)tp * B_ + r) * 1024 + dir * 512);

        u64 hq[32];
#pragma unroll
        for (int it = 0; it < 16; it++) {
            const u64* hp = (const u64*)(hrow + it * 32 + q * 8);
            hq[2 * it]     = aload(hp);
            hq[2 * it + 1] = aload(hp + 1);
        }
        if (s > 0) {
            int tries = 0;
            while (true) {
                bool stale = false;
#pragma unroll
                for (int j = 0; j < 32; j++)
                    stale |= ((unsigned)hq[j] & 0xFFFFu) == 0xFFFFu;
                if (!__any(stale) || ++tries > (1 << 16)) break;
                __builtin_amdgcn_s_sleep(1);
#pragma unroll
                for (int j = 0; j < 32; j++)
                    if (((unsigned)hq[j] & 0xFFFFu) == 0xFFFFu)
                        hq[j] = aload((const u64*)(hrow + (j >> 1) * 32 + q * 8) + (j & 1));
            }
        }

        f32x4 acc[4];
#pragma unroll
        for (int g = 0; g < 4; g++)
#pragma unroll
            for (int rr = 0; rr < 4; rr++) acc[g][rr] = 0.f;

#pragma unroll
        for (int it = 0; it < 16; it++) {
            union { u64 q2[2]; bf16x8 v; } ua;
            ua.q2[0] = hq[2 * it]; ua.q2[1] = hq[2 * it + 1];
#pragma unroll
            for (int g = 0; g < 4; g++) {
                bf16x8 bv = *(const bf16x8*)&Ws[((g * 16 + it) * 64 + lane) * 8];
                acc[g] = __builtin_amdgcn_mfma_f32_16x16x32_bf16(ua.v, bv, acc[g], 0, 0, 0);
            }
        }

        // ---- pointwise gates; h -> LDS transpose tile (parity-buffered)
        short* tb = Tb[s & 1];
#pragma unroll
        for (int rr = 0; rr < 4; rr++) {
            float gi = acc[0][rr] + xw[rr][0];
            float gf = acc[1][rr] + xw[rr][1];
            float gg = acc[2][rr] + xw[rr][2];
            float go = acc[3][rr] + xw[rr][3];
            float cc = fsig(gf) * c[rr] + fsig(gi) * ftanh(gg);
            c[rr] = cc;
            tb[(b0 + rr) * 24 + lm] = f2b(fsig(go) * ftanh(cc));
        }
        __syncthreads();

        // ---- publish h slice: one u64 per thread, fire-and-forget
        {
            const int b = tid >> 2, qd = tid & 3;
            u64 v0 = *(const u64*)&tb[b * 24 + qd * 4];
            astore((u64*)(Hseq + ((size_t)t * B_ + b) * 1024 + dir * 512 + u0 + qd * 4), v0);
        }

        // prefetch next step's packed XW
        if (s < T_ - 1) {
            const int tn = dir ? (T_ - 2 - s) : (s + 1);
            const float* xp = XW + ((size_t)dir * T_ + tn) * (B_ * G4_) + (size_t)ub * 4096;
#pragma unroll
            for (int rr = 0; rr < 4; rr++)
                xw[rr] = *(const f32x4*)(xp + rr * 1024 + tid * 4);
        }
    }
}

// ---------------------------------------------------------------------------
// fp32 GEMM for tiny attention matmuls (bounds-checked), act 0/1/2
// ---------------------------------------------------------------------------
__global__ __launch_bounds__(256) void gemm_bt(
    const float* __restrict__ A, const float* __restrict__ Bm,
    float* __restrict__ C, int M, int N, int K,
    const float* __restrict__ bias1, int act)
{
    __shared__ float As[16][68];
    __shared__ float Bs[16][68];
    const int tid = threadIdx.x;
    const int m_base = blockIdx.y * 64;
    const int n_base = blockIdx.x * 64;
    const int tm = tid >> 4, tn = tid & 15;
    float acc[4][4] = {};

    for (int k0 = 0; k0 < K; k0 += 16) {
#pragma unroll
        for (int i = 0; i < 4; i++) {
            int idx = tid * 4 + i;
            int rr = idx >> 4, kk = idx & 15;
            int gm = m_base + rr, gk = k0 + kk;
            As[kk][rr] = (gm < M && gk < K) ? A[(size_t)gm * K + gk] : 0.f;
            int gn = n_base + rr;
            Bs[kk][rr] = (gn < N && gk < K) ? Bm[(size_t)gn * K + gk] : 0.f;
        }
        __syncthreads();
#pragma unroll
        for (int kk = 0; kk < 16; kk++) {
            float4 av = *(const float4*)&As[kk][tm * 4];
            float4 bv = *(const float4*)&Bs[kk][tn * 4];
            float a[4] = {av.x, av.y, av.z, av.w};
            float b[4] = {bv.x, bv.y, bv.z, bv.w};
#pragma unroll
            for (int i = 0; i < 4; i++)
#pragma unroll
                for (int j = 0; j < 4; j++)
                    acc[i][j] = fmaf(a[i], b[j], acc[i][j]);
        }
        __syncthreads();
    }
#pragma unroll
    for (int i = 0; i < 4; i++) {
        int gm = m_base + tm * 4 + i;
        if (gm >= M) continue;
#pragma unroll
        for (int j = 0; j < 4; j++) {
            int gn = n_base + tn * 4 + j;
            if (gn >= N) continue;
            float v = acc[i][j];
            if (bias1) v += bias1[gn];
            if (act == 1) v = tanhf(v);
            else if (act == 2) v = expf(v);
            C[(size_t)gm * N + gn] = v;
        }
    }
}

// ---------------------------------------------------------------------------
__global__ __launch_bounds__(256) void conv_f2b(
    const float* __restrict__ src, short* __restrict__ dst, int n)
{
    int i = blockIdx.x * 256 + threadIdx.x;
    if (i < n) dst[i] = f2b(src[i]);
}
__global__ __launch_bounds__(256) void conv_f2b_pad(
    const float* __restrict__ src, short* __restrict__ dst,
    int rows, int kin, int kp)
{
    int i = blockIdx.x * 256 + threadIdx.x;
    if (i < rows * kp) {
        int rr = i / kp, k = i % kp;
        dst[i] = (k < kin) ? f2b(src[(size_t)rr * kin + k]) : (short)0;
    }
}

__global__ __launch_bounds__(256) void attn_alpha(
    const float* __restrict__ E, float* __restrict__ AB)
{
    const int b = blockIdx.x, tid = threadIdx.x;
    __shared__ float red[256];
    __shared__ float adj[152];
    float v = 0.f;
    if (tid < 150) {
        int d = tid / F_, j = tid % F_;
        v = E[((size_t)d * B_ + b) * F_ + j];
    }
    red[tid] = v; __syncthreads();
    for (int s2 = 128; s2 > 0; s2 >>= 1) {
        if (tid < s2) red[tid] += red[tid + s2];
        __syncthreads();
    }
    float total = red[0]; __syncthreads();
    float alpha = v / total;
    float m = (tid < 150 && alpha >= 0.1f) ? 1.f : 0.f;
    red[tid] = m; __syncthreads();
    for (int s2 = 128; s2 > 0; s2 >>= 1) {
        if (tid < s2) red[tid] += red[tid + s2];
        __syncthreads();
    }
    float cnt = red[0]; __syncthreads();
    red[tid] = m * alpha; __syncthreads();
    for (int s2 = 128; s2 > 0; s2 >>= 1) {
        if (tid < s2) red[tid] += red[tid + s2];
        __syncthreads();
    }
    float selsum = red[0]; __syncthreads();
    float selmean = selsum / fmaxf(cnt, 1.f);
    if (tid < 150) adj[tid] = (m > 0.f) ? selmean : alpha;
    __syncthreads();
    if (tid < F_) AB[(size_t)b * F_ + tid] = 0.5f * (adj[tid] + adj[F_ + tid]);
}

__global__ __launch_bounds__(256) void scale_xb(
    const float* __restrict__ x, const float* __restrict__ AB,
    short* __restrict__ xb)
{
    int i = blockIdx.x * 256 + threadIdx.x;
    if (i < TB_ * KP_) {
        int rr = i >> 7, k = i & 127;
        if (k < F_) {
            int b = rr % B_;
            xb[i] = f2b(x[(size_t)rr * F_ + k] * AB[(size_t)b * F_ + k]);
        } else xb[i] = 0;
    }
}

// ---------------------------------------------------------------------------
extern "C" void kernel_launch(void* const* d_in, const int* in_sizes, int n_in,
                              void* d_out, int out_size, void* d_ws, size_t ws_size,
                              hipStream_t stream)
{
    (void)in_sizes; (void)n_in; (void)out_size; (void)ws_size;
    const float* x       = (const float*)d_in[0];
    const float* h0      = (const float*)d_in[1];
    const float* c0      = (const float*)d_in[2];
    const float* sa_Wih  = (const float*)d_in[3];
    const float* sa_Whh  = (const float*)d_in[4];
    const float* sa_bih  = (const float*)d_in[5];
    const float* sa_bhh  = (const float*)d_in[6];
    const float* m0_Wih  = (const float*)d_in[7];
    const float* m0_Whh  = (const float*)d_in[8];
    const float* m0_bih  = (const float*)d_in[9];
    const float* m0_bhh  = (const float*)d_in[10];
    const float* mL_Wih  = (const float*)d_in[11];
    const float* mL_Whh  = (const float*)d_in[12];
    const float* mL_bih  = (const float*)d_in[13];
    const float* mL_bhh  = (const float*)d_in[14];
    const float* safc1_W = (const float*)d_in[15];
    const float* safc1_b = (const float*)d_in[16];
    const float* safc2_W = (const float*)d_in[17];
    const float* safc2_b = (const float*)d_in[18];
    const float* fc1_W   = (const float*)d_in[19];
    const float* fc1_b   = (const float*)d_in[20];

    char* cur = (char*)d_ws;
    auto alloc = [&](size_t bytes) {
        char* p = cur; cur += (bytes + 255) & ~(size_t)255; return p;
    };
    const size_t YB = (size_t)TB_ * 2 * H_ * 2;   // 16 MB bf16 seq buffer
    float*    XW   = (float*)alloc((size_t)2 * TB_ * G4_ * 4);   // packed
    float*    T1b  = (float*)alloc(2 * B_ * H_ * 4);
    float*    Eb   = (float*)alloc(2 * B_ * F_ * 4);
    float*    AB   = (float*)alloc(B_ * F_ * 4);
    float*    saHf = (float*)alloc(2 * B_ * H_ * 4);
    short*    xb   = (short*)alloc((size_t)TB_ * KP_ * 2);
    short*    HsA  = (short*)alloc(YB);
    short*    Y0b  = (short*)alloc(YB);
    short*    Y1b  = (short*)alloc(YB);
    short*    Ht0  = (short*)alloc(2 * B_ * H_ * 2);
    short*    Wpk  = (short*)alloc((size_t)2 * G4_ * H_ * 2);
    short*    Wihb = (short*)alloc((size_t)2 * G4_ * KP_ * 2);
    short*    WihbL= (short*)alloc((size_t)2 * G4_ * 2 * H_ * 2);
    short*    fc1b = (short*)alloc((size_t)H_ * 2 * H_ * 2);

    auto cv = [&](const float* s, short* d, int n) {
        conv_f2b<<<(n + 255) / 256, 256, 0, stream>>>(s, d, n);
    };
    auto g16 = [&](const short* Ap, const short* Bp, float* Cp, float* Pp,
                   int M, int N, int K, const float* b1, const float* b2) {
        gemm_bf16<<<dim3(N / 128, M / 128), 256, 0, stream>>>(Ap, Bp, Cp, Pp, M, N, K, b1, b2);
    };
    auto phase = [&](const float* Whh_p, const float* h0p, const float* c0p,
                     short* Hseq) {
        pack_whh<<<(2 * G4_ * H_ + 255) / 256, 256, 0, stream>>>(Whh_p, Wpk);
        init_phase<<<256, 256, 0, stream>>>(h0p, Ht0);
        hipMemsetAsync(Hseq, 0xFF, YB, stream);
        lstm_phase<<<dim3(32, 2), 256, 0, stream>>>(XW, Wpk, Ht0, Hseq, c0p);
    };

    cv(fc1_W, fc1b, H_ * 2 * H_);

    // ---- Phase A: SA BiLSTM ----
    conv_f2b_pad<<<(TB_ * KP_ + 255) / 256, 256, 0, stream>>>(x, xb, TB_, F_, KP_);
    conv_f2b_pad<<<(2 * G4_ * KP_ + 255) / 256, 256, 0, stream>>>(sa_Wih, Wihb, 2 * G4_, F_, KP_);
    for (int d = 0; d < 2; d++)
        g16(xb, Wihb + (size_t)d * G4_ * KP_, nullptr, XW + (size_t)d * TB_ * G4_,
            TB_, G4_, KP_, sa_bih + d * G4_, sa_bhh + d * G4_);
    phase(sa_Whh, h0, c0, HsA);
    extract_sahf<<<256, 256, 0, stream>>>(HsA, saHf);
    gemm_bt<<<dim3(8, 2), 256, 0, stream>>>(saHf, safc1_W, T1b, 2 * B_, H_, H_, safc1_b, 1);
    gemm_bt<<<dim3(2, 2), 256, 0, stream>>>(T1b, safc2_W, Eb, 2 * B_, F_, H_, safc2_b, 2);
    attn_alpha<<<B_, 256, 0, stream>>>(Eb, AB);
    scale_xb<<<(TB_ * KP_ + 255) / 256, 256, 0, stream>>>(x, AB, xb);

    // ---- Phase B: main layer 0 ----
    conv_f2b_pad<<<(2 * G4_ * KP_ + 255) / 256, 256, 0, stream>>>(m0_Wih, Wihb, 2 * G4_, F_, KP_);
    for (int d = 0; d < 2; d++)
        g16(xb, Wihb + (size_t)d * G4_ * KP_, nullptr, XW + (size_t)d * TB_ * G4_,
            TB_, G4_, KP_, m0_bih + d * G4_, m0_bhh + d * G4_);
    phase(m0_Whh, h0, c0, Y0b);

    // ---- Phase C: main layer 1 ----
    cv(mL_Wih, WihbL, 2 * G4_ * 2 * H_);
    for (int d = 0; d < 2; d++)
        g16(Y0b, WihbL + (size_t)d * G4_ * 2 * H_, nullptr, XW + (size_t)d * TB_ * G4_,
            TB_, G4_, 2 * H_, mL_bih + d * G4_, mL_bhh + d * G4_);
    phase(mL_Whh, h0 + 2 * B_ * H_, c0 + 2 * B_ * H_, Y1b);

    // ---- Phase D: main layer 2 ----
    cv(mL_Wih + (size_t)2 * G4_ * 2 * H_, WihbL, 2 * G4_ * 2 * H_);
    for (int d = 0; d < 2; d++)
        g16(Y1b, WihbL + (size_t)d * G4_ * 2 * H_, nullptr, XW + (size_t)d * TB_ * G4_,
            TB_, G4_, 2 * H_, mL_bih + (2 + d) * G4_, mL_bhh + (2 + d) * G4_);
    phase(mL_Whh + (size_t)2 * G4_ * H_, h0 + 4 * B_ * H_, c0 + 4 * B_ * H_, Y0b);

    // ---- FC1 ----
    g16(Y0b, fc1b, (float*)d_out, nullptr, TB_, H_, 2 * H_, fc1_b, nullptr);
}